// Round 6
// baseline (220.871 us; speedup 1.0000x reference)
//
#include <hip/hip_runtime.h>
#include <math.h>

#define B 8
#define S 1024
#define D 1024
#define F 3584

#define KSV 32    // split-K for 1024x1024 matvecs: chunk 32
#define KSG 16    // split-K for gate/up: chunk 64... (chunk = D/KSG = 64? no: chunk 64) -> see CHG
#define KSD 56    // split-K for down: chunk 64
#define CH32 32
#define CHG 64    // gate/up K-chunk (D / KSG)
#define CHD 64    // down K-chunk (F / KSD)

#define LD4(p) (*(const float4*)(p))
#define FMA4(A, s, W) { (A).x += (s)*(W).x; (A).y += (s)*(W).y; (A).z += (s)*(W).z; (A).w += (s)*(W).w; }

// 8-step FMA for token-batch bb against weight regs w0..w7 (k = koff..koff+7).
// xs reads are wave-uniform (token values) -> LDS broadcast, no bank conflicts.
#define BB8(bb, ACC, XS, CH, koff) { \
  float4 xa = LD4((XS) + (bb)*(CH) + (koff)); \
  float4 xb = LD4((XS) + (bb)*(CH) + (koff) + 4); \
  FMA4(ACC, xa.x, w0); FMA4(ACC, xa.y, w1); FMA4(ACC, xa.z, w2); FMA4(ACC, xa.w, w3); \
  FMA4(ACC, xb.x, w4); FMA4(ACC, xb.y, w5); FMA4(ACC, xb.z, w6); FMA4(ACC, xb.w, w7); }

#define ALL8(XS, CH, koff) \
  BB8(0, acc0, XS, CH, koff) BB8(1, acc1, XS, CH, koff) \
  BB8(2, acc2, XS, CH, koff) BB8(3, acc3, XS, CH, koff) \
  BB8(4, acc4, XS, CH, koff) BB8(5, acc5, XS, CH, koff) \
  BB8(6, acc6, XS, CH, koff) BB8(7, acc7, XS, CH, koff)

#define DECL_ACC \
  float4 acc0 = {0,0,0,0}, acc1 = {0,0,0,0}, acc2 = {0,0,0,0}, acc3 = {0,0,0,0}; \
  float4 acc4 = {0,0,0,0}, acc5 = {0,0,0,0}, acc6 = {0,0,0,0}, acc7 = {0,0,0,0};

#define PREFETCH_LOOP(XS, CH, ST) \
  float4 w0 = Wp[0*(ST)], w1 = Wp[1*(ST)], w2 = Wp[2*(ST)], w3 = Wp[3*(ST)]; \
  float4 w4 = Wp[4*(ST)], w5 = Wp[5*(ST)], w6 = Wp[6*(ST)], w7 = Wp[7*(ST)]; \
  Wp += 8 * (ST); \
  _Pragma("unroll") \
  for (int t = 0; t < (CH) / 8 - 1; t++) { \
    float4 n0 = Wp[0*(ST)], n1 = Wp[1*(ST)], n2 = Wp[2*(ST)], n3 = Wp[3*(ST)]; \
    float4 n4 = Wp[4*(ST)], n5 = Wp[5*(ST)], n6 = Wp[6*(ST)], n7 = Wp[7*(ST)]; \
    Wp += 8 * (ST); \
    ALL8(XS, CH, t * 8); \
    w0 = n0; w1 = n1; w2 = n2; w3 = n3; w4 = n4; w5 = n5; w6 = n6; w7 = n7; \
  } \
  ALL8(XS, CH, (CH) - 8);

// ---------------- block-wide sum for 256-thread blocks ----------------
__device__ __forceinline__ float block_sum256(float v, volatile float* buf) {
  #pragma unroll
  for (int o = 32; o; o >>= 1) v += __shfl_down(v, o);   // wave64 reduce
  __syncthreads();
  if ((threadIdx.x & 63) == 0) buf[threadIdx.x >> 6] = v;
  __syncthreads();
  return buf[0] + buf[1] + buf[2] + buf[3];
}

// K1: h1[b] = rmsnorm(hidden[b,0,:], ln1_w).  grid=B, block=256.
__global__ void k_rms1(const float* __restrict__ hs, const float* __restrict__ w,
                       float* __restrict__ h1) {
  __shared__ float buf[4];
  int b = blockIdx.x;
  int idx = threadIdx.x * 4;
  float4 x = LD4(hs + (size_t)b * S * D + idx);
  float ss = x.x * x.x + x.y * x.y + x.z * x.z + x.w * x.w;
  float tot = block_sum256(ss, buf);
  float sc = rsqrtf(tot * (1.f / (float)D) + 1e-6f);
  float4 wv = LD4(w + idx);
  float4 o;
  o.x = x.x * sc * wv.x; o.y = x.y * sc * wv.y;
  o.z = x.z * sc * wv.z; o.w = x.w * sc * wv.w;
  *(float4*)(h1 + b * D + idx) = o;
}

// K2: Vp[p][bb][j] = sum_{i in chunk p} h1[bb][i]*vw[i][j]. grid=KSV, block=256.
__global__ __launch_bounds__(256, 2) void k_mvp(const float* __restrict__ X,
                                                const float* __restrict__ W,
                                                float* __restrict__ P) {
  __shared__ float xs[8 * CH32];
  int i0 = blockIdx.x * CH32;
  xs[threadIdx.x] = X[(threadIdx.x >> 5) * D + i0 + (threadIdx.x & 31)];
  __syncthreads();
  int j = threadIdx.x * 4;
  const float4* Wp = (const float4*)(W + (size_t)i0 * D + j);
  const int st = D / 4;
  DECL_ACC
  PREFETCH_LOOP(xs, CH32, st)
  #define MV_ST(bb, ACC) *(float4*)(P + ((size_t)blockIdx.x * 8 + (bb)) * D + j) = ACC;
  MV_ST(0, acc0) MV_ST(1, acc1) MV_ST(2, acc2) MV_ST(3, acc3)
  MV_ST(4, acc4) MV_ST(5, acc5) MV_ST(6, acc6) MV_ST(7, acc7)
  #undef MV_ST
}

// K3: same matvec but X comes from reducing KSV partials during staging
// (fused k_red8k). Op[p][bb][j] partials of (sum Vp) @ ow. grid=KSV, block=256.
__global__ __launch_bounds__(256, 2) void k_mvp_red(const float* __restrict__ Vp,
                                                    const float* __restrict__ W,
                                                    float* __restrict__ P) {
  __shared__ float xs[8 * CH32];
  int i0 = blockIdx.x * CH32;
  {
    int bb = threadIdx.x >> 5, k = threadIdx.x & 31;
    float s = 0.f;
    #pragma unroll 8
    for (int p = 0; p < KSV; p++)
      s += Vp[((size_t)p * 8 + bb) * D + i0 + k];
    xs[threadIdx.x] = s;
  }
  __syncthreads();
  int j = threadIdx.x * 4;
  const float4* Wp = (const float4*)(W + (size_t)i0 * D + j);
  const int st = D / 4;
  DECL_ACC
  PREFETCH_LOOP(xs, CH32, st)
  #define MV_ST(bb, ACC) *(float4*)(P + ((size_t)blockIdx.x * 8 + (bb)) * D + j) = ACC;
  MV_ST(0, acc0) MV_ST(1, acc1) MV_ST(2, acc2) MV_ST(3, acc3)
  MV_ST(4, acc4) MV_ST(5, acc5) MV_ST(6, acc6) MV_ST(7, acc7)
  #undef MV_ST
}

// K4: xr = hidden[b,0] + sum_p Op; h2 = rmsnorm(xr, ln2); router top-1. grid=B.
__global__ void k_mid(const float* __restrict__ hs, const float* __restrict__ Op,
                      const float* __restrict__ ln2, const float* __restrict__ rw,
                      float* __restrict__ xr, float* __restrict__ h2,
                      float* __restrict__ topw, int* __restrict__ sel) {
  __shared__ float buf[4];
  int b = blockIdx.x;
  int idx = threadIdx.x * 4;
  float4 x = LD4(hs + (size_t)b * S * D + idx);
  #pragma unroll 8
  for (int p = 0; p < KSV; p++) {
    float4 v = LD4(Op + ((size_t)p * 8 + b) * D + idx);
    x.x += v.x; x.y += v.y; x.z += v.z; x.w += v.w;
  }
  *(float4*)(xr + b * D + idx) = x;
  float ss = x.x * x.x + x.y * x.y + x.z * x.z + x.w * x.w;
  float tot = block_sum256(ss, buf);
  float sc = rsqrtf(tot * (1.f / (float)D) + 1e-6f);
  float4 wv = LD4(ln2 + idx);
  float4 h;
  h.x = x.x * sc * wv.x; h.y = x.y * sc * wv.y;
  h.z = x.z * sc * wv.z; h.w = x.w * sc * wv.w;
  *(float4*)(h2 + b * D + idx) = h;
  float r0 = h.x * rw[idx * 2] + h.y * rw[(idx + 1) * 2] +
             h.z * rw[(idx + 2) * 2] + h.w * rw[(idx + 3) * 2];
  float r1 = h.x * rw[idx * 2 + 1] + h.y * rw[(idx + 1) * 2 + 1] +
             h.z * rw[(idx + 2) * 2 + 1] + h.w * rw[(idx + 3) * 2 + 1];
  r0 = block_sum256(r0, buf);
  r1 = block_sum256(r1, buf);
  if (threadIdx.x == 0) {
    float m = fmaxf(r0, r1);
    float e0 = __expf(r0 - m), e1 = __expf(r1 - m);
    float inv = 1.f / (e0 + e1);
    float p0 = e0 * inv, p1 = e1 * inv;
    topw[b] = fmaxf(p0, p1);
    sel[b] = (p1 > p0) ? 1 : 0;
  }
}

// K5: split-K partials over flattened col space of 4 matrices
// (m=0: gate e0, 1: gate e1, 2: up e0, 3: up e1). grid=(14, KSG), block=256.
// Pgu layout [kc][m(4)][bb(8)][F].
__global__ __launch_bounds__(256, 2) void k_gateup(const float* __restrict__ h2,
                                                   const float* __restrict__ gw,
                                                   const float* __restrict__ uw,
                                                   float* __restrict__ Pgu) {
  __shared__ float xs[8 * CHG];
  int i0 = blockIdx.y * CHG;
  {
    int t = threadIdx.x, t2 = threadIdx.x + 256;
    xs[t]  = h2[(t >> 6) * D + i0 + (t & 63)];
    xs[t2] = h2[(t2 >> 6) * D + i0 + (t2 & 63)];
  }
  __syncthreads();
  int c = blockIdx.x * 1024 + threadIdx.x * 4;
  int m = c / F;
  int j = c - m * F;
  const float* base = (m < 2 ? gw : uw) + (size_t)(m & 1) * D * F;
  const float4* Wp = (const float4*)(base + (size_t)i0 * F + j);
  const int st = F / 4;
  DECL_ACC
  PREFETCH_LOOP(xs, CHG, st)
  #define GU_ST(bb, ACC) \
    *(float4*)(Pgu + (((size_t)blockIdx.y * 4 + m) * 8 + (bb)) * F + j) = ACC;
  GU_ST(0, acc0) GU_ST(1, acc1) GU_ST(2, acc2) GU_ST(3, acc3)
  GU_ST(4, acc4) GU_ST(5, acc5) GU_ST(6, acc6) GU_ST(7, acc7)
  #undef GU_ST
}

// K6: down partials, with silu-reduce of Pgu fused into staging (no g buffer).
// grid=(2, KSD), block=256. Dp layout [kc][e? no: [kc][e][bb][D] with kc=blockIdx.y? -> [kc*2+e]
__global__ __launch_bounds__(256, 2) void k_down(const float* __restrict__ Pgu,
                                                 const float* __restrict__ dw,
                                                 float* __restrict__ Dp) {
  __shared__ float xs[8 * CHD];
  int e = blockIdx.x;
  int i0 = blockIdx.y * CHD;
  #pragma unroll
  for (int t = threadIdx.x; t < 8 * CHD; t += 256) {
    int bb = t >> 6, k = t & 63;
    float gs = 0.f, us = 0.f;
    #pragma unroll 8
    for (int kc = 0; kc < KSG; kc++) {
      gs += Pgu[(((size_t)kc * 4 + e)     * 8 + bb) * F + i0 + k];
      us += Pgu[(((size_t)kc * 4 + 2 + e) * 8 + bb) * F + i0 + k];
    }
    xs[t] = (gs / (1.f + __expf(-gs))) * us;   // silu(gate)*up
  }
  __syncthreads();
  int j = threadIdx.x * 4;
  const float4* Wp = (const float4*)(dw + (size_t)e * F * D + (size_t)i0 * D + j);
  const int st = D / 4;
  DECL_ACC
  PREFETCH_LOOP(xs, CHD, st)
  #define DN_ST(bb, ACC) \
    *(float4*)(Dp + (((size_t)blockIdx.y * 2 + e) * 8 + (bb)) * D + j) = ACC;
  DN_ST(0, acc0) DN_ST(1, acc1) DN_ST(2, acc2) DN_ST(3, acc3)
  DN_ST(4, acc4) DN_ST(5, acc5) DN_ST(6, acc6) DN_ST(7, acc7)
  #undef DN_ST
}

// K7: x2 = xr + top_w * sum_p Dp[p][sel]; final rmsnorm; logits. grid=B, block=256.
__global__ void k_final(const float* __restrict__ xr, const float* __restrict__ Dp,
                        const float* __restrict__ topw, const int* __restrict__ sel,
                        const float* __restrict__ flw, const float* __restrict__ sw,
                        float* __restrict__ out) {
  __shared__ float buf[4];
  int b = blockIdx.x;
  int e = sel[b];
  float tw = topw[b];
  int idx = threadIdx.x * 4;
  float4 y = {0,0,0,0};
  #pragma unroll 8
  for (int p = 0; p < KSD; p++) {
    float4 v = LD4(Dp + (((size_t)p * 2 + e) * 8 + b) * D + idx);
    y.x += v.x; y.y += v.y; y.z += v.z; y.w += v.w;
  }
  float4 x = LD4(xr + b * D + idx);
  x.x += tw * y.x; x.y += tw * y.y; x.z += tw * y.z; x.w += tw * y.w;
  float ss = x.x * x.x + x.y * x.y + x.z * x.z + x.w * x.w;
  float tot = block_sum256(ss, buf);
  float sc = rsqrtf(tot * (1.f / (float)D) + 1e-6f);
  float4 wv = LD4(flw + idx);
  float n0 = x.x * sc * wv.x, n1 = x.y * sc * wv.y;
  float n2 = x.z * sc * wv.z, n3 = x.w * sc * wv.w;
  float l0 = n0 * sw[idx * 2] + n1 * sw[(idx + 1) * 2] +
             n2 * sw[(idx + 2) * 2] + n3 * sw[(idx + 3) * 2];
  float l1 = n0 * sw[idx * 2 + 1] + n1 * sw[(idx + 1) * 2 + 1] +
             n2 * sw[(idx + 2) * 2 + 1] + n3 * sw[(idx + 3) * 2 + 1];
  l0 = block_sum256(l0, buf);
  l1 = block_sum256(l1, buf);
  if (threadIdx.x == 0) { out[b * 2 + 0] = l0; out[b * 2 + 1] = l1; }
}

extern "C" void kernel_launch(void* const* d_in, const int* in_sizes, int n_in,
                              void* d_out, int out_size, void* d_ws, size_t ws_size,
                              hipStream_t stream) {
  const float* hs  = (const float*)d_in[0];
  const float* ln1 = (const float*)d_in[1];
  // d_in[2]=q_w, d_in[3]=k_w: dead — token-0 causal attention only needs V.
  const float* vw  = (const float*)d_in[4];
  const float* ow  = (const float*)d_in[5];
  const float* ln2 = (const float*)d_in[6];
  const float* rw  = (const float*)d_in[7];
  const float* gw  = (const float*)d_in[8];
  const float* uw  = (const float*)d_in[9];
  const float* dw  = (const float*)d_in[10];
  const float* flw = (const float*)d_in[11];
  const float* sw  = (const float*)d_in[12];

  float* ws = (float*)d_ws;
  float* h1   = ws;                   // 8192
  float* Vp   = ws + 8192;            // KSV*8*D    = 262144
  float* Op   = ws + 270336;          // 262144
  float* xr   = ws + 532480;          // 8192
  float* h2   = ws + 540672;          // 8192
  float* Pgu  = ws + 548864;          // KSG*4*8*F  = 1835008
  float* Dp   = ws + 2383872;         // KSD*2*8*D  = 917504
  float* topw = ws + 3301376;         // 8
  int*   sel  = (int*)(ws + 3301384); // 8
  // no atomics -> no zero-init; every partial cell is written before read.

  k_rms1<<<8, 256, 0, stream>>>(hs, ln1, h1);
  k_mvp<<<KSV, 256, 0, stream>>>(h1, vw, Vp);
  k_mvp_red<<<KSV, 256, 0, stream>>>(Vp, ow, Op);   // fused Vp-reduce + @o_w
  k_mid<<<8, 256, 0, stream>>>(hs, Op, ln2, rw, xr, h2, topw, sel);
  k_gateup<<<dim3(14, KSG), 256, 0, stream>>>(h2, gw, uw, Pgu);
  k_down<<<dim3(2, KSD), 256, 0, stream>>>(Pgu, dw, Dp);  // fused silu-reduce + @down_w
  k_final<<<8, 256, 0, stream>>>(xr, Dp, topw, sel, flw, sw, (float*)d_out);
}

// Round 7
// 206.592 us; speedup vs baseline: 1.0691x; 1.0691x over previous
//
#include <hip/hip_runtime.h>
#include <math.h>

#define B 8
#define S 1024
#define D 1024
#define F 3584

#define KSV 64    // split-K for 1024x1024 matvecs: chunk 16
#define CHV 16
#define KSG 32    // split-K for gate/up: chunk 32
#define KSD 112   // split-K for down: chunk 32
#define CH32 32

#define LD4(p) (*(const float4*)(p))
#define FMA4(A, s, W) { (A).x += (s)*(W).x; (A).y += (s)*(W).y; (A).z += (s)*(W).z; (A).w += (s)*(W).w; }

// 8-step FMA for token-batch bb against weight regs w0..w7 (k = koff..koff+7).
#define BB8(bb, ACC, XS, CH, koff) { \
  float4 xa = LD4((XS) + (bb)*(CH) + (koff)); \
  float4 xb = LD4((XS) + (bb)*(CH) + (koff) + 4); \
  FMA4(ACC, xa.x, w0); FMA4(ACC, xa.y, w1); FMA4(ACC, xa.z, w2); FMA4(ACC, xa.w, w3); \
  FMA4(ACC, xb.x, w4); FMA4(ACC, xb.y, w5); FMA4(ACC, xb.z, w6); FMA4(ACC, xb.w, w7); }

#define ALL8(XS, CH, koff) \
  BB8(0, acc0, XS, CH, koff) BB8(1, acc1, XS, CH, koff) \
  BB8(2, acc2, XS, CH, koff) BB8(3, acc3, XS, CH, koff) \
  BB8(4, acc4, XS, CH, koff) BB8(5, acc5, XS, CH, koff) \
  BB8(6, acc6, XS, CH, koff) BB8(7, acc7, XS, CH, koff)

#define DECL_ACC \
  float4 acc0 = {0,0,0,0}, acc1 = {0,0,0,0}, acc2 = {0,0,0,0}, acc3 = {0,0,0,0}; \
  float4 acc4 = {0,0,0,0}, acc5 = {0,0,0,0}, acc6 = {0,0,0,0}, acc7 = {0,0,0,0};

// Rotated prefetch: 8 weight float4s in flight while computing previous 8.
#define PREFETCH_LOOP(XS, CH, ST) \
  float4 w0 = Wp[0*(ST)], w1 = Wp[1*(ST)], w2 = Wp[2*(ST)], w3 = Wp[3*(ST)]; \
  float4 w4 = Wp[4*(ST)], w5 = Wp[5*(ST)], w6 = Wp[6*(ST)], w7 = Wp[7*(ST)]; \
  Wp += 8 * (ST); \
  _Pragma("unroll") \
  for (int t = 0; t < (CH) / 8 - 1; t++) { \
    float4 n0 = Wp[0*(ST)], n1 = Wp[1*(ST)], n2 = Wp[2*(ST)], n3 = Wp[3*(ST)]; \
    float4 n4 = Wp[4*(ST)], n5 = Wp[5*(ST)], n6 = Wp[6*(ST)], n7 = Wp[7*(ST)]; \
    Wp += 8 * (ST); \
    ALL8(XS, CH, t * 8); \
    w0 = n0; w1 = n1; w2 = n2; w3 = n3; w4 = n4; w5 = n5; w6 = n6; w7 = n7; \
  } \
  ALL8(XS, CH, (CH) - 8);

// ---------------- block-wide sum for 256-thread blocks ----------------
__device__ __forceinline__ float block_sum256(float v, volatile float* buf) {
  #pragma unroll
  for (int o = 32; o; o >>= 1) v += __shfl_down(v, o);   // wave64 reduce
  __syncthreads();
  if ((threadIdx.x & 63) == 0) buf[threadIdx.x >> 6] = v;
  __syncthreads();
  return buf[0] + buf[1] + buf[2] + buf[3];
}

// K1: fused rms1 + v_w matvec partials. grid=KSV, block=256.
// Each block redundantly computes rmsnorm scales (32KB re-read, L3-resident),
// stages its K-slice of h1 = rms(hs_tok0)*ln1, streams 16x1024 of v_w.
__global__ __launch_bounds__(256, 2) void k_v(const float* __restrict__ hs,
                                              const float* __restrict__ ln1,
                                              const float* __restrict__ W,
                                              float* __restrict__ P) {
  __shared__ float sq[256];
  __shared__ float scale[8];
  __shared__ float xs[8 * CHV];
  int i0 = blockIdx.x * CHV;
  {
    int b = threadIdx.x >> 5, l = threadIdx.x & 31;
    const float* xrow = hs + (size_t)b * S * D + l * 32;
    float ss = 0.f;
    #pragma unroll
    for (int u = 0; u < 8; u++) {
      float4 v = LD4(xrow + u * 4);
      ss += v.x * v.x + v.y * v.y + v.z * v.z + v.w * v.w;
    }
    sq[threadIdx.x] = ss;
  }
  __syncthreads();
  if (threadIdx.x < 8) {
    float s = 0.f;
    #pragma unroll
    for (int u = 0; u < 32; u++) s += sq[threadIdx.x * 32 + u];
    scale[threadIdx.x] = rsqrtf(s * (1.f / (float)D) + 1e-6f);
  }
  __syncthreads();
  if (threadIdx.x < 8 * CHV) {
    int bb = threadIdx.x >> 4, k = threadIdx.x & 15;
    xs[threadIdx.x] = hs[(size_t)bb * S * D + i0 + k] * scale[bb] * ln1[i0 + k];
  }
  __syncthreads();
  int j = threadIdx.x * 4;
  const float4* Wp = (const float4*)(W + (size_t)i0 * D + j);
  const int st = D / 4;
  DECL_ACC
  PREFETCH_LOOP(xs, CHV, st)
  #define MV_ST(bb, ACC) *(float4*)(P + ((size_t)blockIdx.x * 8 + (bb)) * D + j) = ACC;
  MV_ST(0, acc0) MV_ST(1, acc1) MV_ST(2, acc2) MV_ST(3, acc3)
  MV_ST(4, acc4) MV_ST(5, acc5) MV_ST(6, acc6) MV_ST(7, acc7)
  #undef MV_ST
}

// K2: fused Vp-reduce + o_w matvec partials. grid=KSV, block=256.
// Staging sums the KSV partials for this block's K-slice (4-way partial accs,
// all loads independent), then streams 16x1024 of o_w.
__global__ __launch_bounds__(256, 2) void k_o(const float* __restrict__ Vp,
                                              const float* __restrict__ W,
                                              float* __restrict__ P) {
  __shared__ float xs[8 * CHV];
  int i0 = blockIdx.x * CHV;
  if (threadIdx.x < 8 * CHV) {
    int bb = threadIdx.x >> 4, k = threadIdx.x & 15;
    const float* src = Vp + (size_t)bb * D + i0 + k;
    float s0 = 0.f, s1 = 0.f, s2 = 0.f, s3 = 0.f;
    #pragma unroll 4
    for (int p = 0; p < KSV; p += 4) {
      s0 += src[(size_t)(p + 0) * 8 * D];
      s1 += src[(size_t)(p + 1) * 8 * D];
      s2 += src[(size_t)(p + 2) * 8 * D];
      s3 += src[(size_t)(p + 3) * 8 * D];
    }
    xs[threadIdx.x] = (s0 + s1) + (s2 + s3);
  }
  __syncthreads();
  int j = threadIdx.x * 4;
  const float4* Wp = (const float4*)(W + (size_t)i0 * D + j);
  const int st = D / 4;
  DECL_ACC
  PREFETCH_LOOP(xs, CHV, st)
  #define MV_ST(bb, ACC) *(float4*)(P + ((size_t)blockIdx.x * 8 + (bb)) * D + j) = ACC;
  MV_ST(0, acc0) MV_ST(1, acc1) MV_ST(2, acc2) MV_ST(3, acc3)
  MV_ST(4, acc4) MV_ST(5, acc5) MV_ST(6, acc6) MV_ST(7, acc7)
  #undef MV_ST
}

// K3: xr = hidden[b,0] + sum_p Op; h2 = rmsnorm(xr, ln2); router top-1. grid=B.
__global__ void k_mid(const float* __restrict__ hs, const float* __restrict__ Op,
                      const float* __restrict__ ln2, const float* __restrict__ rw,
                      float* __restrict__ xr, float* __restrict__ h2,
                      float* __restrict__ topw, int* __restrict__ sel) {
  __shared__ float buf[4];
  int b = blockIdx.x;
  int idx = threadIdx.x * 4;
  float4 x = LD4(hs + (size_t)b * S * D + idx);
  #pragma unroll 8
  for (int p = 0; p < KSV; p++) {
    float4 v = LD4(Op + ((size_t)p * 8 + b) * D + idx);
    x.x += v.x; x.y += v.y; x.z += v.z; x.w += v.w;
  }
  *(float4*)(xr + b * D + idx) = x;
  float ss = x.x * x.x + x.y * x.y + x.z * x.z + x.w * x.w;
  float tot = block_sum256(ss, buf);
  float sc = rsqrtf(tot * (1.f / (float)D) + 1e-6f);
  float4 wv = LD4(ln2 + idx);
  float4 h;
  h.x = x.x * sc * wv.x; h.y = x.y * sc * wv.y;
  h.z = x.z * sc * wv.z; h.w = x.w * sc * wv.w;
  *(float4*)(h2 + b * D + idx) = h;
  float r0 = h.x * rw[idx * 2] + h.y * rw[(idx + 1) * 2] +
             h.z * rw[(idx + 2) * 2] + h.w * rw[(idx + 3) * 2];
  float r1 = h.x * rw[idx * 2 + 1] + h.y * rw[(idx + 1) * 2 + 1] +
             h.z * rw[(idx + 2) * 2 + 1] + h.w * rw[(idx + 3) * 2 + 1];
  r0 = block_sum256(r0, buf);
  r1 = block_sum256(r1, buf);
  if (threadIdx.x == 0) {
    float m = fmaxf(r0, r1);
    float e0 = __expf(r0 - m), e1 = __expf(r1 - m);
    float inv = 1.f / (e0 + e1);
    float p0 = e0 * inv, p1 = e1 * inv;
    topw[b] = fmaxf(p0, p1);
    sel[b] = (p1 > p0) ? 1 : 0;
  }
}

// K4: split-K partials over flattened col space of 4 matrices
// (m=0: gate e0, 1: gate e1, 2: up e0, 3: up e1). grid=(14, KSG), block=256.
// Pgu layout [kc][m(4)][bb(8)][F].
__global__ __launch_bounds__(256, 2) void k_gateup(const float* __restrict__ h2,
                                                   const float* __restrict__ gw,
                                                   const float* __restrict__ uw,
                                                   float* __restrict__ Pgu) {
  __shared__ float xs[8 * CH32];
  int i0 = blockIdx.y * CH32;
  xs[threadIdx.x] = h2[(threadIdx.x >> 5) * D + i0 + (threadIdx.x & 31)];
  __syncthreads();
  int c = blockIdx.x * 1024 + threadIdx.x * 4;
  int m = c / F;
  int j = c - m * F;
  const float* base = (m < 2 ? gw : uw) + (size_t)(m & 1) * D * F;
  const float4* Wp = (const float4*)(base + (size_t)i0 * F + j);
  const int st = F / 4;
  DECL_ACC
  PREFETCH_LOOP(xs, CH32, st)
  #define GU_ST(bb, ACC) \
    *(float4*)(Pgu + (((size_t)blockIdx.y * 4 + m) * 8 + (bb)) * F + j) = ACC;
  GU_ST(0, acc0) GU_ST(1, acc1) GU_ST(2, acc2) GU_ST(3, acc3)
  GU_ST(4, acc4) GU_ST(5, acc5) GU_ST(6, acc6) GU_ST(7, acc7)
  #undef GU_ST
}

// K5: g[e][bb][j] = silu(sum_kc gate) * (sum_kc up). grid=56, block=256.
__global__ void k_silu_red(const float* __restrict__ Pgu, float* __restrict__ g) {
  int o = blockIdx.x * 256 + threadIdx.x;     // float4 idx in [0, 14336)
  int e = o / (8 * F / 4);                     // 0..1
  int rem = o - e * (8 * F / 4);
  const float4* P4 = (const float4*)Pgu;
  float4 ga = {0,0,0,0}, ua = {0,0,0,0};
  #pragma unroll 8
  for (int kc = 0; kc < KSG; kc++) {
    float4 gv = P4[(size_t)(kc * 4 + e)     * (8 * F / 4) + rem];
    float4 uv = P4[(size_t)(kc * 4 + 2 + e) * (8 * F / 4) + rem];
    ga.x += gv.x; ga.y += gv.y; ga.z += gv.z; ga.w += gv.w;
    ua.x += uv.x; ua.y += uv.y; ua.z += uv.z; ua.w += uv.w;
  }
  float4 r;
  r.x = (ga.x / (1.f + __expf(-ga.x))) * ua.x;
  r.y = (ga.y / (1.f + __expf(-ga.y))) * ua.y;
  r.z = (ga.z / (1.f + __expf(-ga.z))) * ua.z;
  r.w = (ga.w / (1.f + __expf(-ga.w))) * ua.w;
  ((float4*)g)[o] = r;
}

// K6: split-K partials of g[e][b] @ down_w[e]. grid=(2, KSD), block=256.
__global__ __launch_bounds__(256, 2) void k_down(const float* __restrict__ g,
                                                 const float* __restrict__ dw,
                                                 float* __restrict__ Dp) {
  __shared__ float xs[8 * CH32];
  int e = blockIdx.x;
  int i0 = blockIdx.y * CH32;
  xs[threadIdx.x] = g[(size_t)e * 8 * F + (threadIdx.x >> 5) * F + i0 + (threadIdx.x & 31)];
  __syncthreads();
  int j = threadIdx.x * 4;
  const float4* Wp = (const float4*)(dw + (size_t)e * F * D + (size_t)i0 * D + j);
  const int st = D / 4;
  DECL_ACC
  PREFETCH_LOOP(xs, CH32, st)
  #define DN_ST(bb, ACC) \
    *(float4*)(Dp + (((size_t)blockIdx.y * 2 + e) * 8 + (bb)) * D + j) = ACC;
  DN_ST(0, acc0) DN_ST(1, acc1) DN_ST(2, acc2) DN_ST(3, acc3)
  DN_ST(4, acc4) DN_ST(5, acc5) DN_ST(6, acc6) DN_ST(7, acc7)
  #undef DN_ST
}

// K7: x2 = xr + top_w * sum_p Dp[p][sel]; final rmsnorm; logits. grid=B, block=256.
__global__ void k_final(const float* __restrict__ xr, const float* __restrict__ Dp,
                        const float* __restrict__ topw, const int* __restrict__ sel,
                        const float* __restrict__ flw, const float* __restrict__ sw,
                        float* __restrict__ out) {
  __shared__ float buf[4];
  int b = blockIdx.x;
  int e = sel[b];
  float tw = topw[b];
  int idx = threadIdx.x * 4;
  float4 y = {0,0,0,0};
  #pragma unroll 8
  for (int p = 0; p < KSD; p++) {
    float4 v = LD4(Dp + (((size_t)p * 2 + e) * 8 + b) * D + idx);
    y.x += v.x; y.y += v.y; y.z += v.z; y.w += v.w;
  }
  float4 x = LD4(xr + b * D + idx);
  x.x += tw * y.x; x.y += tw * y.y; x.z += tw * y.z; x.w += tw * y.w;
  float ss = x.x * x.x + x.y * x.y + x.z * x.z + x.w * x.w;
  float tot = block_sum256(ss, buf);
  float sc = rsqrtf(tot * (1.f / (float)D) + 1e-6f);
  float4 wv = LD4(flw + idx);
  float n0 = x.x * sc * wv.x, n1 = x.y * sc * wv.y;
  float n2 = x.z * sc * wv.z, n3 = x.w * sc * wv.w;
  float l0 = n0 * sw[idx * 2] + n1 * sw[(idx + 1) * 2] +
             n2 * sw[(idx + 2) * 2] + n3 * sw[(idx + 3) * 2];
  float l1 = n0 * sw[idx * 2 + 1] + n1 * sw[(idx + 1) * 2 + 1] +
             n2 * sw[(idx + 2) * 2 + 1] + n3 * sw[(idx + 3) * 2 + 1];
  l0 = block_sum256(l0, buf);
  l1 = block_sum256(l1, buf);
  if (threadIdx.x == 0) { out[b * 2 + 0] = l0; out[b * 2 + 1] = l1; }
}

extern "C" void kernel_launch(void* const* d_in, const int* in_sizes, int n_in,
                              void* d_out, int out_size, void* d_ws, size_t ws_size,
                              hipStream_t stream) {
  const float* hs  = (const float*)d_in[0];
  const float* ln1 = (const float*)d_in[1];
  // d_in[2]=q_w, d_in[3]=k_w: dead — token-0 causal attention only needs V.
  const float* vw  = (const float*)d_in[4];
  const float* ow  = (const float*)d_in[5];
  const float* ln2 = (const float*)d_in[6];
  const float* rw  = (const float*)d_in[7];
  const float* gw  = (const float*)d_in[8];
  const float* uw  = (const float*)d_in[9];
  const float* dw  = (const float*)d_in[10];
  const float* flw = (const float*)d_in[11];
  const float* sw  = (const float*)d_in[12];

  float* ws = (float*)d_ws;
  float* Vp   = ws;                   // KSV*8*D    = 524288
  float* Op   = ws + 524288;          // 524288
  float* xr   = ws + 1048576;         // 8192
  float* h2   = ws + 1056768;         // 8192
  float* Pgu  = ws + 1064960;         // KSG*4*8*F  = 3670016
  float* g    = ws + 4734976;         // 2*8*F      = 57344
  float* Dp   = ws + 4792320;         // KSD*2*8*D  = 1835008
  float* topw = ws + 6627328;         // 8
  int*   sel  = (int*)(ws + 6627336); // 8
  // no atomics -> no zero-init; every partial cell is written before read.

  k_v<<<KSV, 256, 0, stream>>>(hs, ln1, vw, Vp);          // fused rms1 + @v_w
  k_o<<<KSV, 256, 0, stream>>>(Vp, ow, Op);               // fused Vp-reduce + @o_w
  k_mid<<<8, 256, 0, stream>>>(hs, Op, ln2, rw, xr, h2, topw, sel);
  k_gateup<<<dim3(14, KSG), 256, 0, stream>>>(h2, gw, uw, Pgu);
  k_silu_red<<<56, 256, 0, stream>>>(Pgu, g);
  k_down<<<dim3(2, KSD), 256, 0, stream>>>(g, dw, Dp);
  k_final<<<8, 256, 0, stream>>>(xr, Dp, topw, sel, flw, sw, (float*)d_out);
}